// Round 9
// baseline (376.730 us; speedup 1.0000x reference)
//
#include <hip/hip_runtime.h>

#define N_NODES 100000
#define N_EDGES 1600000
#define F_IN 256
#define F_HID 128
#define F_OUT 32
#define NBUCK 391           // ceil(100000/256) buckets of 256 node ids
#define BIN_BLOCKS 512
#define EDGES_PER_BIN 3125  // 512*3125 = 1,600,000

typedef unsigned short ushort_t;
typedef unsigned int uint_t;

using short8  = __attribute__((ext_vector_type(8))) short;
using floatx4 = __attribute__((ext_vector_type(4))) float;

__device__ __forceinline__ ushort_t f2bf(float f) {
    uint_t u = __float_as_uint(f);
    u += 0x7fff + ((u >> 16) & 1);  // RNE
    return (ushort_t)(u >> 16);
}
__device__ __forceinline__ float bf_lo(uint_t u) { return __uint_as_float(u << 16); }
__device__ __forceinline__ float bf_hi(uint_t u) { return __uint_as_float(u & 0xffff0000u); }

// ---------------- CSR pass 1 (blocks 0..511) + weight transpose (blocks 512..543) ----------------
__global__ __launch_bounds__(256) void histwt_kernel(const int* __restrict__ ei,
                                                     int* __restrict__ bucket_cnt,
                                                     const float* __restrict__ W1,
                                                     const float* __restrict__ W2,
                                                     ushort_t* __restrict__ W1T,
                                                     ushort_t* __restrict__ W2T) {
    __shared__ int h[NBUCK];
    if (blockIdx.x < BIN_BLOCKS) {
        for (int i = threadIdx.x; i < NBUCK; i += 256) h[i] = 0;
        __syncthreads();
        int gid = blockIdx.x * 256 + threadIdx.x;
        for (int e = gid; e < N_EDGES; e += BIN_BLOCKS * 256)
            atomicAdd(&h[ei[N_EDGES + e] >> 8], 1);
        __syncthreads();
        for (int i = threadIdx.x; i < NBUCK; i += 256) {
            int c = h[i];
            if (c) atomicAdd(&bucket_cnt[i], c);
        }
    } else {
        int t = (blockIdx.x - BIN_BLOCKS) * 256 + threadIdx.x;  // 0..8191
#pragma unroll
        for (int j = 0; j < 4; j++) {
            int e = j * 8192 + t;                // e = n*256 + k
            int n = e >> 8, k = e & 255;
            W1T[e] = f2bf(W1[k * F_HID + n]);
        }
        if (t < 4096) {
            int n = t >> 7, k = t & 127;
            W2T[t] = f2bf(W2[k * F_OUT + n]);
        }
    }
}

// ---------------- CSR build: scan bucket counts ----------------
__global__ __launch_bounds__(512) void scan_kernel(const int* __restrict__ bucket_cnt,
                                                   int* __restrict__ bucket_base,
                                                   int* __restrict__ bucket_cursor,
                                                   int* __restrict__ offs) {
    __shared__ int s[512];
    int t = threadIdx.x;
    int own = (t < NBUCK) ? bucket_cnt[t] : 0;
    s[t] = own;
    __syncthreads();
    for (int off = 1; off < 512; off <<= 1) {
        int v = (t >= off) ? s[t - off] : 0;
        __syncthreads();
        s[t] += v;
        __syncthreads();
    }
    if (t < NBUCK) {
        int ex = s[t] - own;
        bucket_base[t] = ex;
        bucket_cursor[t] = ex;
    }
    if (t == 0) {
        bucket_base[NBUCK] = N_EDGES;
        offs[N_NODES] = N_EDGES;
    }
}

// ---------------- CSR build, pass 2: bin edges into bucket regions ----------------
__global__ __launch_bounds__(256) void bin_kernel(const int* __restrict__ ei,
                                                  int* __restrict__ bucket_cursor,
                                                  int2* __restrict__ binned) {
    __shared__ int h[NBUCK];
    __shared__ int base[NBUCK];
    const int t = threadIdx.x;
    const int beg = blockIdx.x * EDGES_PER_BIN;
    const int end = beg + EDGES_PER_BIN;
    for (int i = t; i < NBUCK; i += 256) h[i] = 0;
    __syncthreads();
    for (int e = beg + t; e < end; e += 256) atomicAdd(&h[ei[N_EDGES + e] >> 8], 1);
    __syncthreads();
    for (int i = t; i < NBUCK; i += 256) {
        int c = h[i];
        base[i] = c ? atomicAdd(&bucket_cursor[i], c) : 0;
        h[i] = 0;
    }
    __syncthreads();
    for (int e = beg + t; e < end; e += 256) {
        int s = ei[e], d = ei[N_EDGES + e];
        int bk = d >> 8;
        int p = base[bk] + atomicAdd(&h[bk], 1);
        binned[p] = make_int2(s, d);
    }
}

// ---------------- CSR build, pass 3: per-bucket offs/dinv/csr ----------------
__global__ __launch_bounds__(256) void build_kernel(const int2* __restrict__ binned,
                                                    const int* __restrict__ bucket_base,
                                                    int* __restrict__ offs,
                                                    int* __restrict__ csr,
                                                    float* __restrict__ dinv) {
    __shared__ int h[256];
    __shared__ int sc[256];
    __shared__ int cur[256];
    const int b = blockIdx.x, t = threadIdx.x;
    const int beg = bucket_base[b];
    const int end = bucket_base[b + 1];
    h[t] = 0;
    __syncthreads();
    for (int j = beg + t; j < end; j += 256) {
        int2 p = binned[j];
        atomicAdd(&h[p.y & 255], 1);
    }
    __syncthreads();
    int deg = h[t];
    sc[t] = deg;
    __syncthreads();
    for (int off = 1; off < 256; off <<= 1) {
        int v = (t >= off) ? sc[t - off] : 0;
        __syncthreads();
        sc[t] += v;
        __syncthreads();
    }
    int excl = sc[t] - deg;
    cur[t] = excl;
    int node = b * 256 + t;
    if (node < N_NODES) {
        offs[node] = beg + excl;
        dinv[node] = rsqrtf((float)deg + 1.0f);  // +1 self-loop
    }
    __syncthreads();
    for (int j = beg + t; j < end; j += 256) {
        int2 p = binned[j];
        int pos = atomicAdd(&cur[p.y & 255], 1);
        csr[beg + pos] = p.x;
    }
}

// ---------------- GEMM1 (MFMA, 512 threads): h0 = bf16(x @ W1) ----------------
// Block: 128 rows x 128 cols, 8 waves. 66 KB LDS -> 2 blocks/CU = 16 waves/CU.
__global__ __launch_bounds__(512) void gemm1_kernel(const float* __restrict__ x,
                                                    const ushort_t* __restrict__ W1T,
                                                    ushort_t* __restrict__ h0bf) {
    __shared__ ushort_t Bst[F_HID][F_IN + 8];  // 128 x 264 bf16 = 66 KB
    const int tid = threadIdx.x;
    const int rbase = blockIdx.x * 128;
    const int w = tid >> 6;        // wave 0..7
    const int lane = tid & 63;
    const int q = lane >> 4;       // quad 0..3
    const int nloc = lane & 15;    // 0..15

    // stage W1T -> LDS (4096 x 16B, coalesced; 8 per thread)
#pragma unroll
    for (int j = 0; j < 8; j++) {
        int f = j * 512 + tid;           // 0..4095
        int n = f >> 5, kg = f & 31;     // kg: 8-bf16 group
        uint4 v = ((const uint4*)(W1T + n * F_IN))[kg];
        *(uint4*)(&Bst[n][kg * 8]) = v;
    }
    __syncthreads();

    const int rowA = rbase + w * 16 + nloc;
    const bool okA = rowA < N_NODES;
    const float* ap = x + (size_t)rowA * F_IN + q * 8;

    floatx4 acc[8];
#pragma unroll
    for (int t = 0; t < 8; t++) acc[t] = (floatx4){0.f, 0.f, 0.f, 0.f};

#pragma unroll
    for (int k0 = 0; k0 < F_IN; k0 += 32) {
        float4 f0 = make_float4(0.f, 0.f, 0.f, 0.f);
        float4 f1 = make_float4(0.f, 0.f, 0.f, 0.f);
        if (okA) {
            f0 = *(const float4*)(ap + k0);
            f1 = *(const float4*)(ap + k0 + 4);
        }
        short8 a;
        a[0] = (short)f2bf(f0.x); a[1] = (short)f2bf(f0.y);
        a[2] = (short)f2bf(f0.z); a[3] = (short)f2bf(f0.w);
        a[4] = (short)f2bf(f1.x); a[5] = (short)f2bf(f1.y);
        a[6] = (short)f2bf(f1.z); a[7] = (short)f2bf(f1.w);
#pragma unroll
        for (int t = 0; t < 8; t++) {
            short8 b = *(const short8*)(&Bst[t * 16 + nloc][k0 + q * 8]);
            acc[t] = __builtin_amdgcn_mfma_f32_16x16x32_bf16(a, b, acc[t], 0, 0, 0);
        }
    }

    // D layout: col = lane&15 (n within tile), row = q*4 + reg
#pragma unroll
    for (int reg = 0; reg < 4; reg++) {
        int rowD = rbase + w * 16 + q * 4 + reg;
        if (rowD < N_NODES) {
            ushort_t* op = h0bf + (size_t)rowD * F_HID + nloc;
#pragma unroll
            for (int t = 0; t < 8; t++) op[t * 16] = f2bf(acc[t][reg]);
        }
    }
}

// ---------------- FUSED: gather layer-1 agg -> LDS -> MFMA with W2 -> h2bf ----------------
// Block = 64 nodes. Phase A: 8 half-waves gather 8 agg rows each (unroll-4),
// apply b1+relu, pack bf16 into LDS. Phase B: gemm2 MFMA from LDS.
__global__ __launch_bounds__(256) void gg2_kernel(const ushort_t* __restrict__ h0bf,
                                                  const int* __restrict__ offs,
                                                  const int* __restrict__ csr,
                                                  const float* __restrict__ dinv,
                                                  const float* __restrict__ b1,
                                                  const ushort_t* __restrict__ W2T,
                                                  ushort_t* __restrict__ h2bf) {
    __shared__ ushort_t As[64][F_HID + 8];     // 64 x 136 bf16 = 17.4 KB
    __shared__ ushort_t Bs[F_OUT][F_HID + 8];  // 32 x 136 bf16 = 8.7 KB
    const int tid = threadIdx.x;
    const int rbase = blockIdx.x * 64;

    // stage W2T: 32 rows x 16 uint4 = 512, 2 per thread
#pragma unroll
    for (int jj = 0; jj < 2; jj++) {
        int f = jj * 256 + tid;       // 0..511
        int n = f >> 4, kg = f & 15;
        uint4 v = ((const uint4*)(W2T + n * F_HID))[kg];
        *(uint4*)(&Bs[n][kg * 8]) = v;
    }

    // ---- Phase A: gather 8 nodes per half-wave ----
    const int hw = tid >> 5;   // 0..7
    const int l = tid & 31;
    const float4 b1v = *(const float4*)(b1 + l * 4);

    for (int u = 0; u < 8; u++) {
        int node = rbase + hw * 8 + u;
        float4 acc = make_float4(0.f, 0.f, 0.f, 0.f);
        if (node < N_NODES) {
            float dn = dinv[node];
            uint2 sv = ((const uint2*)(h0bf + (size_t)node * F_HID))[l];
            float s = dn * dn;
            acc.x = bf_lo(sv.x) * s; acc.y = bf_hi(sv.x) * s;
            acc.z = bf_lo(sv.y) * s; acc.w = bf_hi(sv.y) * s;

            int beg = offs[node], end = offs[node + 1];
            int j = beg;
            for (; j + 3 < end; j += 4) {
                int s0 = csr[j], s1 = csr[j + 1], s2 = csr[j + 2], s3 = csr[j + 3];
                float n0 = dinv[s0] * dn, n1 = dinv[s1] * dn;
                float n2 = dinv[s2] * dn, n3 = dinv[s3] * dn;
                uint2 v0 = ((const uint2*)(h0bf + (size_t)s0 * F_HID))[l];
                uint2 v1 = ((const uint2*)(h0bf + (size_t)s1 * F_HID))[l];
                uint2 v2 = ((const uint2*)(h0bf + (size_t)s2 * F_HID))[l];
                uint2 v3 = ((const uint2*)(h0bf + (size_t)s3 * F_HID))[l];
                acc.x += bf_lo(v0.x) * n0 + bf_lo(v1.x) * n1 + bf_lo(v2.x) * n2 + bf_lo(v3.x) * n3;
                acc.y += bf_hi(v0.x) * n0 + bf_hi(v1.x) * n1 + bf_hi(v2.x) * n2 + bf_hi(v3.x) * n3;
                acc.z += bf_lo(v0.y) * n0 + bf_lo(v1.y) * n1 + bf_lo(v2.y) * n2 + bf_lo(v3.y) * n3;
                acc.w += bf_hi(v0.y) * n0 + bf_hi(v1.y) * n1 + bf_hi(v2.y) * n2 + bf_hi(v3.y) * n3;
            }
            for (; j < end; j++) {
                int s0 = csr[j];
                float n0 = dinv[s0] * dn;
                uint2 v0 = ((const uint2*)(h0bf + (size_t)s0 * F_HID))[l];
                acc.x += bf_lo(v0.x) * n0; acc.y += bf_hi(v0.x) * n0;
                acc.z += bf_lo(v0.y) * n0; acc.w += bf_hi(v0.y) * n0;
            }
        }
        // bias + relu + pack to LDS
        uint2 p;
        p.x = (uint_t)f2bf(fmaxf(acc.x + b1v.x, 0.f)) |
              ((uint_t)f2bf(fmaxf(acc.y + b1v.y, 0.f)) << 16);
        p.y = (uint_t)f2bf(fmaxf(acc.z + b1v.z, 0.f)) |
              ((uint_t)f2bf(fmaxf(acc.w + b1v.w, 0.f)) << 16);
        *(uint2*)(&As[hw * 8 + u][l * 4]) = p;
    }
    __syncthreads();

    // ---- Phase B: MFMA ----
    const int w = tid >> 6;
    const int lane = tid & 63;
    const int q = lane >> 4;
    const int nloc = lane & 15;

    floatx4 acc2[2];
    acc2[0] = (floatx4){0.f, 0.f, 0.f, 0.f};
    acc2[1] = (floatx4){0.f, 0.f, 0.f, 0.f};

#pragma unroll
    for (int k0 = 0; k0 < F_HID; k0 += 32) {
        int kk = k0 + q * 8;
        short8 a = *(const short8*)(&As[w * 16 + nloc][kk]);
#pragma unroll
        for (int t = 0; t < 2; t++) {
            short8 b = *(const short8*)(&Bs[t * 16 + nloc][kk]);
            acc2[t] = __builtin_amdgcn_mfma_f32_16x16x32_bf16(a, b, acc2[t], 0, 0, 0);
        }
    }
#pragma unroll
    for (int reg = 0; reg < 4; reg++) {
        int rowD = rbase + w * 16 + q * 4 + reg;
        if (rowD < N_NODES) {
            ushort_t* op = h2bf + (size_t)rowD * F_OUT + nloc;
            op[0]  = f2bf(acc2[0][reg]);
            op[16] = f2bf(acc2[1][reg]);
        }
    }
}

// ---------------- gather aggregation layer 2 + bias + log_softmax (unroll-4) ----------------
__global__ __launch_bounds__(256) void gather32_lsm(const ushort_t* __restrict__ h2bf,
                                                    const int* __restrict__ offs,
                                                    const int* __restrict__ csr,
                                                    const float* __restrict__ dinv,
                                                    const float* __restrict__ b2,
                                                    float* __restrict__ out) {
    int node = blockIdx.x * 32 + (threadIdx.x >> 3);
    int l = threadIdx.x & 7;
    float dn = dinv[node];
    uint2 sv = ((const uint2*)(h2bf + (size_t)node * F_OUT))[l];
    float s = dn * dn;
    float4 acc;
    acc.x = bf_lo(sv.x) * s; acc.y = bf_hi(sv.x) * s;
    acc.z = bf_lo(sv.y) * s; acc.w = bf_hi(sv.y) * s;

    int beg = offs[node], end = offs[node + 1];
    int j = beg;
    for (; j + 3 < end; j += 4) {
        int s0 = csr[j], s1 = csr[j + 1], s2 = csr[j + 2], s3 = csr[j + 3];
        float n0 = dinv[s0] * dn, n1 = dinv[s1] * dn;
        float n2 = dinv[s2] * dn, n3 = dinv[s3] * dn;
        uint2 v0 = ((const uint2*)(h2bf + (size_t)s0 * F_OUT))[l];
        uint2 v1 = ((const uint2*)(h2bf + (size_t)s1 * F_OUT))[l];
        uint2 v2 = ((const uint2*)(h2bf + (size_t)s2 * F_OUT))[l];
        uint2 v3 = ((const uint2*)(h2bf + (size_t)s3 * F_OUT))[l];
        acc.x += bf_lo(v0.x) * n0 + bf_lo(v1.x) * n1 + bf_lo(v2.x) * n2 + bf_lo(v3.x) * n3;
        acc.y += bf_hi(v0.x) * n0 + bf_hi(v1.x) * n1 + bf_hi(v2.x) * n2 + bf_hi(v3.x) * n3;
        acc.z += bf_lo(v0.y) * n0 + bf_lo(v1.y) * n1 + bf_lo(v2.y) * n2 + bf_lo(v3.y) * n3;
        acc.w += bf_hi(v0.y) * n0 + bf_hi(v1.y) * n1 + bf_hi(v2.y) * n2 + bf_hi(v3.y) * n3;
    }
    for (; j < end; j++) {
        int s0 = csr[j];
        float n0 = dinv[s0] * dn;
        uint2 v0 = ((const uint2*)(h2bf + (size_t)s0 * F_OUT))[l];
        acc.x += bf_lo(v0.x) * n0; acc.y += bf_hi(v0.x) * n0;
        acc.z += bf_lo(v0.y) * n0; acc.w += bf_hi(v0.y) * n0;
    }
    float4 bb = ((const float4*)b2)[l];
    acc.x += bb.x; acc.y += bb.y; acc.z += bb.z; acc.w += bb.w;

    float m = fmaxf(fmaxf(acc.x, acc.y), fmaxf(acc.z, acc.w));
#pragma unroll
    for (int off = 1; off < 8; off <<= 1) m = fmaxf(m, __shfl_xor(m, off, 8));
    float es = __expf(acc.x - m) + __expf(acc.y - m) + __expf(acc.z - m) + __expf(acc.w - m);
#pragma unroll
    for (int off = 1; off < 8; off <<= 1) es += __shfl_xor(es, off, 8);
    float lse = m + __logf(es);
    float4 o = make_float4(acc.x - lse, acc.y - lse, acc.z - lse, acc.w - lse);
    ((float4*)(out + (size_t)node * F_OUT))[l] = o;
}

extern "C" void kernel_launch(void* const* d_in, const int* in_sizes, int n_in,
                              void* d_out, int out_size, void* d_ws, size_t ws_size,
                              hipStream_t stream) {
    const float* x  = (const float*)d_in[0];
    const int*   ei = (const int*)d_in[1];
    const float* W1 = (const float*)d_in[2];
    const float* b1 = (const float*)d_in[3];
    const float* W2 = (const float*)d_in[4];
    const float* b2 = (const float*)d_in[5];
    float* out = (float*)d_out;

    // workspace layout (4B units)
    float* ws = (float*)d_ws;
    float*    dinv          = ws;                      // 100096
    int*      offs          = (int*)(ws + 100096);     // 100128
    int*      bucket_cnt    = (int*)(ws + 200224);     // 512
    int*      bucket_base   = (int*)(ws + 200736);     // 512
    int*      bucket_cursor = (int*)(ws + 201248);     // 512
    int*      csr           = (int*)(ws + 201760);     // 1,600,000
    ushort_t* W1T           = (ushort_t*)(ws + 1801760);   // 32768 ushort
    ushort_t* W2T           = (ushort_t*)(ws + 1818144);   // 4096 ushort
    ushort_t* h0bf          = (ushort_t*)(ws + 1820192);   // 12.8M ushort
    int2*     binned        = (int2*)(ws + 8220192);       // 1.6M int2 (scratch)
    ushort_t* h2bf          = (ushort_t*)(ws + 14620192);  // 3.2M ushort

    hipMemsetAsync(bucket_cnt, 0, 512 * sizeof(int), stream);
    histwt_kernel<<<BIN_BLOCKS + 32, 256, 0, stream>>>(ei, bucket_cnt, W1, W2, W1T, W2T);
    scan_kernel<<<1, 512, 0, stream>>>(bucket_cnt, bucket_base, bucket_cursor, offs);
    bin_kernel<<<BIN_BLOCKS, 256, 0, stream>>>(ei, bucket_cursor, binned);
    build_kernel<<<NBUCK, 256, 0, stream>>>(binned, bucket_base, offs, csr, dinv);
    gemm1_kernel<<<(N_NODES + 127) / 128, 512, 0, stream>>>(x, W1T, h0bf);
    gg2_kernel<<<(N_NODES + 63) / 64, 256, 0, stream>>>(h0bf, offs, csr, dinv, b1, W2T, h2bf);
    gather32_lsm<<<N_NODES / 32, 256, 0, stream>>>(h2bf, offs, csr, dinv, b2, out);
}

// Round 10
// 349.855 us; speedup vs baseline: 1.0768x; 1.0768x over previous
//
#include <hip/hip_runtime.h>

#define N_NODES 100000
#define N_EDGES 1600000
#define F_IN 256
#define F_HID 128
#define F_OUT 32
#define NBUCK 391           // ceil(100000/256) buckets of 256 node ids
#define BIN_BLOCKS 512
#define EDGES_PER_BIN 3125  // 512*3125 = 1,600,000

typedef unsigned short ushort_t;
typedef unsigned int uint_t;

using short8  = __attribute__((ext_vector_type(8))) short;
using floatx4 = __attribute__((ext_vector_type(4))) float;

__device__ __forceinline__ ushort_t f2bf(float f) {
    uint_t u = __float_as_uint(f);
    u += 0x7fff + ((u >> 16) & 1);  // RNE
    return (ushort_t)(u >> 16);
}
__device__ __forceinline__ float bf_lo(uint_t u) { return __uint_as_float(u << 16); }
__device__ __forceinline__ float bf_hi(uint_t u) { return __uint_as_float(u & 0xffff0000u); }
// pack hi16(b):hi16(a) into one uint via v_perm_b32 (truncating bf16 x2, 1 instr)
__device__ __forceinline__ uint_t bfpack_trunc(float a, float b) {
    return __builtin_amdgcn_perm(__float_as_uint(b), __float_as_uint(a), 0x07060302u);
}

// ---------------- CSR pass 1 (blocks 0..511) + weight transpose (blocks 512..543) ----------------
__global__ __launch_bounds__(256) void histwt_kernel(const int* __restrict__ ei,
                                                     int* __restrict__ bucket_cnt,
                                                     const float* __restrict__ W1,
                                                     const float* __restrict__ W2,
                                                     ushort_t* __restrict__ W1T,
                                                     ushort_t* __restrict__ W2T) {
    __shared__ int h[NBUCK];
    if (blockIdx.x < BIN_BLOCKS) {
        for (int i = threadIdx.x; i < NBUCK; i += 256) h[i] = 0;
        __syncthreads();
        int gid = blockIdx.x * 256 + threadIdx.x;
        for (int e = gid; e < N_EDGES; e += BIN_BLOCKS * 256)
            atomicAdd(&h[ei[N_EDGES + e] >> 8], 1);
        __syncthreads();
        for (int i = threadIdx.x; i < NBUCK; i += 256) {
            int c = h[i];
            if (c) atomicAdd(&bucket_cnt[i], c);
        }
    } else {
        int t = (blockIdx.x - BIN_BLOCKS) * 256 + threadIdx.x;  // 0..8191
#pragma unroll
        for (int j = 0; j < 4; j++) {
            int e = j * 8192 + t;                // e = n*256 + k
            int n = e >> 8, k = e & 255;
            W1T[e] = f2bf(W1[k * F_HID + n]);
        }
        if (t < 4096) {
            int n = t >> 7, k = t & 127;
            W2T[t] = f2bf(W2[k * F_OUT + n]);
        }
    }
}

// ---------------- CSR build: scan bucket counts ----------------
__global__ __launch_bounds__(512) void scan_kernel(const int* __restrict__ bucket_cnt,
                                                   int* __restrict__ bucket_base,
                                                   int* __restrict__ bucket_cursor,
                                                   int* __restrict__ offs) {
    __shared__ int s[512];
    int t = threadIdx.x;
    int own = (t < NBUCK) ? bucket_cnt[t] : 0;
    s[t] = own;
    __syncthreads();
    for (int off = 1; off < 512; off <<= 1) {
        int v = (t >= off) ? s[t - off] : 0;
        __syncthreads();
        s[t] += v;
        __syncthreads();
    }
    if (t < NBUCK) {
        int ex = s[t] - own;
        bucket_base[t] = ex;
        bucket_cursor[t] = ex;
    }
    if (t == 0) {
        bucket_base[NBUCK] = N_EDGES;
        offs[N_NODES] = N_EDGES;
    }
}

// ---------------- CSR build, pass 2: bin edges into bucket regions ----------------
__global__ __launch_bounds__(256) void bin_kernel(const int* __restrict__ ei,
                                                  int* __restrict__ bucket_cursor,
                                                  int2* __restrict__ binned) {
    __shared__ int h[NBUCK];
    __shared__ int base[NBUCK];
    const int t = threadIdx.x;
    const int beg = blockIdx.x * EDGES_PER_BIN;
    const int end = beg + EDGES_PER_BIN;
    for (int i = t; i < NBUCK; i += 256) h[i] = 0;
    __syncthreads();
    for (int e = beg + t; e < end; e += 256) atomicAdd(&h[ei[N_EDGES + e] >> 8], 1);
    __syncthreads();
    for (int i = t; i < NBUCK; i += 256) {
        int c = h[i];
        base[i] = c ? atomicAdd(&bucket_cursor[i], c) : 0;
        h[i] = 0;
    }
    __syncthreads();
    for (int e = beg + t; e < end; e += 256) {
        int s = ei[e], d = ei[N_EDGES + e];
        int bk = d >> 8;
        int p = base[bk] + atomicAdd(&h[bk], 1);
        binned[p] = make_int2(s, d);
    }
}

// ---------------- CSR build, pass 3: per-bucket offs/dinv/csr ----------------
__global__ __launch_bounds__(256) void build_kernel(const int2* __restrict__ binned,
                                                    const int* __restrict__ bucket_base,
                                                    int* __restrict__ offs,
                                                    int* __restrict__ csr,
                                                    float* __restrict__ dinv) {
    __shared__ int h[256];
    __shared__ int sc[256];
    __shared__ int cur[256];
    const int b = blockIdx.x, t = threadIdx.x;
    const int beg = bucket_base[b];
    const int end = bucket_base[b + 1];
    h[t] = 0;
    __syncthreads();
    for (int j = beg + t; j < end; j += 256) {
        int2 p = binned[j];
        atomicAdd(&h[p.y & 255], 1);
    }
    __syncthreads();
    int deg = h[t];
    sc[t] = deg;
    __syncthreads();
    for (int off = 1; off < 256; off <<= 1) {
        int v = (t >= off) ? sc[t - off] : 0;
        __syncthreads();
        sc[t] += v;
        __syncthreads();
    }
    int excl = sc[t] - deg;
    cur[t] = excl;
    int node = b * 256 + t;
    if (node < N_NODES) {
        offs[node] = beg + excl;
        dinv[node] = rsqrtf((float)deg + 1.0f);  // +1 self-loop
    }
    __syncthreads();
    for (int j = beg + t; j < end; j += 256) {
        int2 p = binned[j];
        int pos = atomicAdd(&cur[p.y & 255], 1);
        csr[beg + pos] = p.x;
    }
}

// ---------------- GEMM1 (MFMA, 512 threads): h0 = bf16(x @ W1) ----------------
// Block: 128 rows x 128 cols, 8 waves. 66 KB LDS -> 2 blocks/CU = 16 waves/CU.
// A-fragments packed fp32->bf16 via v_perm_b32 truncation (1 instr / 2 floats).
__global__ __launch_bounds__(512) void gemm1_kernel(const float* __restrict__ x,
                                                    const ushort_t* __restrict__ W1T,
                                                    ushort_t* __restrict__ h0bf) {
    __shared__ ushort_t Bst[F_HID][F_IN + 8];  // 128 x 264 bf16 = 66 KB
    const int tid = threadIdx.x;
    const int rbase = blockIdx.x * 128;
    const int w = tid >> 6;        // wave 0..7
    const int lane = tid & 63;
    const int q = lane >> 4;       // quad 0..3
    const int nloc = lane & 15;    // 0..15

    // stage W1T -> LDS (4096 x 16B, coalesced; 8 per thread)
#pragma unroll
    for (int j = 0; j < 8; j++) {
        int f = j * 512 + tid;           // 0..4095
        int n = f >> 5, kg = f & 31;     // kg: 8-bf16 group
        uint4 v = ((const uint4*)(W1T + n * F_IN))[kg];
        *(uint4*)(&Bst[n][kg * 8]) = v;
    }
    __syncthreads();

    const int rowA = rbase + w * 16 + nloc;
    const bool okA = rowA < N_NODES;
    const float* ap = x + (size_t)rowA * F_IN + q * 8;

    floatx4 acc[8];
#pragma unroll
    for (int t = 0; t < 8; t++) acc[t] = (floatx4){0.f, 0.f, 0.f, 0.f};

#pragma unroll
    for (int k0 = 0; k0 < F_IN; k0 += 32) {
        float4 f0 = make_float4(0.f, 0.f, 0.f, 0.f);
        float4 f1 = make_float4(0.f, 0.f, 0.f, 0.f);
        if (okA) {
            f0 = *(const float4*)(ap + k0);
            f1 = *(const float4*)(ap + k0 + 4);
        }
        uint4 au;
        au.x = bfpack_trunc(f0.x, f0.y);
        au.y = bfpack_trunc(f0.z, f0.w);
        au.z = bfpack_trunc(f1.x, f1.y);
        au.w = bfpack_trunc(f1.z, f1.w);
        short8 a = *(short8*)&au;
#pragma unroll
        for (int t = 0; t < 8; t++) {
            short8 b = *(const short8*)(&Bst[t * 16 + nloc][k0 + q * 8]);
            acc[t] = __builtin_amdgcn_mfma_f32_16x16x32_bf16(a, b, acc[t], 0, 0, 0);
        }
    }

    // D layout: col = lane&15 (n within tile), row = q*4 + reg
#pragma unroll
    for (int reg = 0; reg < 4; reg++) {
        int rowD = rbase + w * 16 + q * 4 + reg;
        if (rowD < N_NODES) {
            ushort_t* op = h0bf + (size_t)rowD * F_HID + nloc;
#pragma unroll
            for (int t = 0; t < 8; t++) op[t * 16] = f2bf(acc[t][reg]);
        }
    }
}

// ---------------- gather aggregation layer 1 (bf16 rows, fp32 acc, unroll-4) ----------------
__global__ __launch_bounds__(256) void gather128(const ushort_t* __restrict__ h0bf,
                                                 const int* __restrict__ offs,
                                                 const int* __restrict__ csr,
                                                 const float* __restrict__ dinv,
                                                 ushort_t* __restrict__ aggbf) {
    int node = blockIdx.x * 8 + (threadIdx.x >> 5);
    int l = threadIdx.x & 31;
    float dn = dinv[node];
    uint2 sv = ((const uint2*)(h0bf + (size_t)node * F_HID))[l];
    float s = dn * dn;
    float4 acc;
    acc.x = bf_lo(sv.x) * s; acc.y = bf_hi(sv.x) * s;
    acc.z = bf_lo(sv.y) * s; acc.w = bf_hi(sv.y) * s;

    int beg = offs[node], end = offs[node + 1];
    int j = beg;
    for (; j + 3 < end; j += 4) {
        int s0 = csr[j], s1 = csr[j + 1], s2 = csr[j + 2], s3 = csr[j + 3];
        float n0 = dinv[s0] * dn, n1 = dinv[s1] * dn;
        float n2 = dinv[s2] * dn, n3 = dinv[s3] * dn;
        uint2 v0 = ((const uint2*)(h0bf + (size_t)s0 * F_HID))[l];
        uint2 v1 = ((const uint2*)(h0bf + (size_t)s1 * F_HID))[l];
        uint2 v2 = ((const uint2*)(h0bf + (size_t)s2 * F_HID))[l];
        uint2 v3 = ((const uint2*)(h0bf + (size_t)s3 * F_HID))[l];
        acc.x += bf_lo(v0.x) * n0 + bf_lo(v1.x) * n1 + bf_lo(v2.x) * n2 + bf_lo(v3.x) * n3;
        acc.y += bf_hi(v0.x) * n0 + bf_hi(v1.x) * n1 + bf_hi(v2.x) * n2 + bf_hi(v3.x) * n3;
        acc.z += bf_lo(v0.y) * n0 + bf_lo(v1.y) * n1 + bf_lo(v2.y) * n2 + bf_lo(v3.y) * n3;
        acc.w += bf_hi(v0.y) * n0 + bf_hi(v1.y) * n1 + bf_hi(v2.y) * n2 + bf_hi(v3.y) * n3;
    }
    for (; j < end; j++) {
        int s0 = csr[j];
        float n0 = dinv[s0] * dn;
        uint2 v0 = ((const uint2*)(h0bf + (size_t)s0 * F_HID))[l];
        acc.x += bf_lo(v0.x) * n0; acc.y += bf_hi(v0.x) * n0;
        acc.z += bf_lo(v0.y) * n0; acc.w += bf_hi(v0.y) * n0;
    }
    uint2 p;
    p.x = (uint_t)f2bf(acc.x) | ((uint_t)f2bf(acc.y) << 16);
    p.y = (uint_t)f2bf(acc.z) | ((uint_t)f2bf(acc.w) << 16);
    ((uint2*)(aggbf + (size_t)node * F_HID))[l] = p;
}

// ---------------- GEMM2 (MFMA): h2 = bf16(relu(agg + b1) @ W2) ----------------
__global__ __launch_bounds__(256) void gemm2_kernel(const ushort_t* __restrict__ aggbf,
                                                    const float* __restrict__ b1,
                                                    const ushort_t* __restrict__ W2T,
                                                    ushort_t* __restrict__ h2bf) {
    __shared__ ushort_t Bs[F_OUT][F_HID + 8];  // 32 x 136 bf16 = 8.7 KB
    __shared__ float b1s[F_HID];
    const int tid = threadIdx.x;
    const int rbase = blockIdx.x * 64;
    const int w = tid >> 6;
    const int lane = tid & 63;
    const int q = lane >> 4;
    const int nloc = lane & 15;

    if (tid < F_HID) b1s[tid] = b1[tid];
#pragma unroll
    for (int jj = 0; jj < 2; jj++) {
        int f = jj * 256 + tid;       // 0..511
        int n = f >> 4, kg = f & 15;
        uint4 v = ((const uint4*)(W2T + n * F_HID))[kg];
        *(uint4*)(&Bs[n][kg * 8]) = v;
    }
    __syncthreads();

    const int rowA = rbase + w * 16 + nloc;
    const bool okA = rowA < N_NODES;

    floatx4 acc[2];
    acc[0] = (floatx4){0.f, 0.f, 0.f, 0.f};
    acc[1] = (floatx4){0.f, 0.f, 0.f, 0.f};

#pragma unroll
    for (int k0 = 0; k0 < F_HID; k0 += 32) {
        int kk = k0 + q * 8;
        uint4 av = make_uint4(0, 0, 0, 0);
        if (okA) av = *(const uint4*)(aggbf + (size_t)rowA * F_HID + kk);
        float4 bb0 = *(const float4*)(&b1s[kk]);
        float4 bb1 = *(const float4*)(&b1s[kk + 4]);
        uint4 au;
        au.x = bfpack_trunc(fmaxf(bf_lo(av.x) + bb0.x, 0.f), fmaxf(bf_hi(av.x) + bb0.y, 0.f));
        au.y = bfpack_trunc(fmaxf(bf_lo(av.y) + bb0.z, 0.f), fmaxf(bf_hi(av.y) + bb0.w, 0.f));
        au.z = bfpack_trunc(fmaxf(bf_lo(av.z) + bb1.x, 0.f), fmaxf(bf_hi(av.z) + bb1.y, 0.f));
        au.w = bfpack_trunc(fmaxf(bf_lo(av.w) + bb1.z, 0.f), fmaxf(bf_hi(av.w) + bb1.w, 0.f));
        short8 a = *(short8*)&au;
#pragma unroll
        for (int t = 0; t < 2; t++) {
            short8 b = *(const short8*)(&Bs[t * 16 + nloc][kk]);
            acc[t] = __builtin_amdgcn_mfma_f32_16x16x32_bf16(a, b, acc[t], 0, 0, 0);
        }
    }
#pragma unroll
    for (int reg = 0; reg < 4; reg++) {
        int rowD = rbase + w * 16 + q * 4 + reg;
        if (rowD < N_NODES) {
            ushort_t* op = h2bf + (size_t)rowD * F_OUT + nloc;
            op[0]  = f2bf(acc[0][reg]);
            op[16] = f2bf(acc[1][reg]);
        }
    }
}

// ---------------- gather aggregation layer 2 + bias + log_softmax (unroll-4) ----------------
__global__ __launch_bounds__(256) void gather32_lsm(const ushort_t* __restrict__ h2bf,
                                                    const int* __restrict__ offs,
                                                    const int* __restrict__ csr,
                                                    const float* __restrict__ dinv,
                                                    const float* __restrict__ b2,
                                                    float* __restrict__ out) {
    int node = blockIdx.x * 32 + (threadIdx.x >> 3);
    int l = threadIdx.x & 7;
    float dn = dinv[node];
    uint2 sv = ((const uint2*)(h2bf + (size_t)node * F_OUT))[l];
    float s = dn * dn;
    float4 acc;
    acc.x = bf_lo(sv.x) * s; acc.y = bf_hi(sv.x) * s;
    acc.z = bf_lo(sv.y) * s; acc.w = bf_hi(sv.y) * s;

    int beg = offs[node], end = offs[node + 1];
    int j = beg;
    for (; j + 3 < end; j += 4) {
        int s0 = csr[j], s1 = csr[j + 1], s2 = csr[j + 2], s3 = csr[j + 3];
        float n0 = dinv[s0] * dn, n1 = dinv[s1] * dn;
        float n2 = dinv[s2] * dn, n3 = dinv[s3] * dn;
        uint2 v0 = ((const uint2*)(h2bf + (size_t)s0 * F_OUT))[l];
        uint2 v1 = ((const uint2*)(h2bf + (size_t)s1 * F_OUT))[l];
        uint2 v2 = ((const uint2*)(h2bf + (size_t)s2 * F_OUT))[l];
        uint2 v3 = ((const uint2*)(h2bf + (size_t)s3 * F_OUT))[l];
        acc.x += bf_lo(v0.x) * n0 + bf_lo(v1.x) * n1 + bf_lo(v2.x) * n2 + bf_lo(v3.x) * n3;
        acc.y += bf_hi(v0.x) * n0 + bf_hi(v1.x) * n1 + bf_hi(v2.x) * n2 + bf_hi(v3.x) * n3;
        acc.z += bf_lo(v0.y) * n0 + bf_lo(v1.y) * n1 + bf_lo(v2.y) * n2 + bf_lo(v3.y) * n3;
        acc.w += bf_hi(v0.y) * n0 + bf_hi(v1.y) * n1 + bf_hi(v2.y) * n2 + bf_hi(v3.y) * n3;
    }
    for (; j < end; j++) {
        int s0 = csr[j];
        float n0 = dinv[s0] * dn;
        uint2 v0 = ((const uint2*)(h2bf + (size_t)s0 * F_OUT))[l];
        acc.x += bf_lo(v0.x) * n0; acc.y += bf_hi(v0.x) * n0;
        acc.z += bf_lo(v0.y) * n0; acc.w += bf_hi(v0.y) * n0;
    }
    float4 bb = ((const float4*)b2)[l];
    acc.x += bb.x; acc.y += bb.y; acc.z += bb.z; acc.w += bb.w;

    float m = fmaxf(fmaxf(acc.x, acc.y), fmaxf(acc.z, acc.w));
#pragma unroll
    for (int off = 1; off < 8; off <<= 1) m = fmaxf(m, __shfl_xor(m, off, 8));
    float es = __expf(acc.x - m) + __expf(acc.y - m) + __expf(acc.z - m) + __expf(acc.w - m);
#pragma unroll
    for (int off = 1; off < 8; off <<= 1) es += __shfl_xor(es, off, 8);
    float lse = m + __logf(es);
    float4 o = make_float4(acc.x - lse, acc.y - lse, acc.z - lse, acc.w - lse);
    ((float4*)(out + (size_t)node * F_OUT))[l] = o;
}

extern "C" void kernel_launch(void* const* d_in, const int* in_sizes, int n_in,
                              void* d_out, int out_size, void* d_ws, size_t ws_size,
                              hipStream_t stream) {
    const float* x  = (const float*)d_in[0];
    const int*   ei = (const int*)d_in[1];
    const float* W1 = (const float*)d_in[2];
    const float* b1 = (const float*)d_in[3];
    const float* W2 = (const float*)d_in[4];
    const float* b2 = (const float*)d_in[5];
    float* out = (float*)d_out;

    // workspace layout (4B units)
    float* ws = (float*)d_ws;
    float*    dinv          = ws;                      // 100096
    int*      offs          = (int*)(ws + 100096);     // 100128
    int*      bucket_cnt    = (int*)(ws + 200224);     // 512
    int*      bucket_base   = (int*)(ws + 200736);     // 512
    int*      bucket_cursor = (int*)(ws + 201248);     // 512
    int*      csr           = (int*)(ws + 201760);     // 1,600,000
    ushort_t* W1T           = (ushort_t*)(ws + 1801760);   // 32768 ushort
    ushort_t* W2T           = (ushort_t*)(ws + 1818144);   // 4096 ushort
    ushort_t* h0bf          = (ushort_t*)(ws + 1820192);   // 12.8M ushort
    ushort_t* aggbf         = (ushort_t*)(ws + 8220192);   // 12.8M ushort
    ushort_t* h2bf          = (ushort_t*)(ws + 14620192);  // 3.2M ushort
    int2*     binned        = (int2*)aggbf;                // alias: dead before gather128 writes agg

    hipMemsetAsync(bucket_cnt, 0, 512 * sizeof(int), stream);
    histwt_kernel<<<BIN_BLOCKS + 32, 256, 0, stream>>>(ei, bucket_cnt, W1, W2, W1T, W2T);
    scan_kernel<<<1, 512, 0, stream>>>(bucket_cnt, bucket_base, bucket_cursor, offs);
    bin_kernel<<<BIN_BLOCKS, 256, 0, stream>>>(ei, bucket_cursor, binned);
    build_kernel<<<NBUCK, 256, 0, stream>>>(binned, bucket_base, offs, csr, dinv);
    gemm1_kernel<<<(N_NODES + 127) / 128, 512, 0, stream>>>(x, W1T, h0bf);
    gather128<<<N_NODES / 8, 256, 0, stream>>>(h0bf, offs, csr, dinv, aggbf);
    gemm2_kernel<<<(N_NODES + 63) / 64, 256, 0, stream>>>(aggbf, b1, W2T, h2bf);
    gather32_lsm<<<N_NODES / 32, 256, 0, stream>>>(h2bf, offs, csr, dinv, b2, out);
}